// Round 19
// baseline (81.193 us; speedup 1.0000x reference)
//
#include <hip/hip_runtime.h>
#include <hip/hip_bf16.h>
#include <math.h>

// SelfRetentionV1: B=2,H=16,L=2048,DK=128,DV=128
// out[b,l,h,d] = RMSNorm_d( (QK^T * gamma^(i-j) / max(1,|rowsum|)) @ V )
#define B_ 2
#define H_ 16
#define L_ 2048
#define DK_ 128
#define DV_ 128
#define QBLK 64
#define KVBLK 64

typedef __bf16 bf16x8 __attribute__((ext_vector_type(8)));
typedef float  f32x16 __attribute__((ext_vector_type(16)));

static __device__ __forceinline__ unsigned short f2bf(float f) {
    union { float f; unsigned int u; } x; x.f = f;
    unsigned int r = x.u + 0x7fffu + ((x.u >> 16) & 1u);  // RNE
    return (unsigned short)(r >> 16);
}

// async global->LDS, 16B per lane; LDS dest = wave-uniform base + lane*16
static __device__ __forceinline__ void gload_lds16(const void* g, void* l) {
    __builtin_amdgcn_global_load_lds(
        (const __attribute__((address_space(1))) unsigned int*)g,
        (__attribute__((address_space(3))) unsigned int*)l,
        16, 0, 0);
}

// K tile rows are 256B: swizzle bits 4-6 by row&7 (involution, row bits >=8)
#define KSWZ(d) ((d) ^ ((((d) >> 8) & 7) << 4))
// V tile rows are 128B: row bits >=7
#define VSWZ(d) ((d) ^ ((((d) >> 7) & 7) << 4))

// ---- fused pre-pass: blocks 0..1023 convert K fp32->bf16 SCALED BY
// gamma_h^-(j&63); 1024..2047 transpose V -> VT[bh][dv][perm(l)]
// (bit2<->3 perm); 2048..2079 fp32 row-0 fixup ----
__global__ void prep_kernel(const float* __restrict__ kin,
                            unsigned short* __restrict__ kb,
                            const float* __restrict__ v,
                            unsigned short* __restrict__ vt,
                            const float* __restrict__ q,
                            float* __restrict__ out) {
    __shared__ unsigned short lds[64][130];   // +2 pad (transpose half only)
    int bid = blockIdx.x;
    if (bid >= 2048) {                 // row-0 fixup, 32 blocks, wave 0 only
        if (threadIdx.x < 64) {
            int bh = bid - 2048;
            int lane = threadIdx.x;
            const float* qp = q   + (size_t)bh * L_ * DK_;
            const float* kp = kin + (size_t)bh * L_ * DK_;
            const float* vp = v   + (size_t)bh * L_ * DV_;
            float part = qp[lane] * kp[lane] + qp[lane + 64] * kp[lane + 64];
            #pragma unroll
            for (int mm = 1; mm < 64; mm <<= 1) part += __shfl_xor(part, mm);
            float cf = part / fmaxf(1.0f, fabsf(part));
            float o0 = cf * vp[lane], o1 = cf * vp[lane + 64];
            float ss = o0 * o0 + o1 * o1;
            #pragma unroll
            for (int mm = 1; mm < 64; mm <<= 1) ss += __shfl_xor(ss, mm);
            float sc = rsqrtf(ss * (1.0f / 128.0f) + 1e-6f);
            int b = bh >> 4, h = bh & 15;
            float* op = out + ((size_t)b * L_ * H_ + h) * DV_;   // i = 0
            op[lane] = o0 * sc;
            op[lane + 64] = o1 * sc;
        }
        return;
    }
    if (bid < 1024) {
        // element layout [b][h][l][dk]: j = (i>>5)&2047, h = (i>>16)&15
        int n4 = B_ * H_ * L_ * DK_ / 4;
        int i = bid * 256 + threadIdx.x;
        int stride = 1024 * 256;
        for (; i < n4; i += stride) {
            int j = (i >> 5) & (L_ - 1);
            int h = (i >> 16) & (H_ - 1);
            float l2g = log1pf(-exp2f((float)(-5 - h))) * 1.44269504088896f;
            float s = exp2f(l2g * -(float)(j & 63));   // gamma^-(j mod 64)
            float4 f = ((const float4*)kin)[i];
            uint2 o;
            o.x = (unsigned)f2bf(f.x * s) | ((unsigned)f2bf(f.y * s) << 16);
            o.y = (unsigned)f2bf(f.z * s) | ((unsigned)f2bf(f.w * s) << 16);
            ((uint2*)kb)[i] = o;
        }
        return;
    }
    int blk = bid - 1024;
    int ltile = blk & (L_/64 - 1);
    int bh = blk / (L_/64);
    const float* vp = v + ((size_t)bh * L_ + (size_t)ltile * 64) * DV_;
    unsigned short* vo = vt + (size_t)bh * DV_ * L_ + ltile * 64;
    int t = threadIdx.x;
    int r0 = t >> 5, c0 = (t & 31) * 4;
    #pragma unroll
    for (int it = 0; it < 8; ++it) {
        int row = r0 + 8 * it;
        float4 f = *(const float4*)(vp + row * DV_ + c0);
        lds[row][c0 + 0] = f2bf(f.x);
        lds[row][c0 + 1] = f2bf(f.y);
        lds[row][c0 + 2] = f2bf(f.z);
        lds[row][c0 + 3] = f2bf(f.w);
    }
    __syncthreads();
    int dvb = t >> 3, seg = t & 7;
    #pragma unroll
    for (int ot = 0; ot < 4; ++ot) {
        int dv = dvb + 32 * ot;
        unsigned short a[8];
        #pragma unroll
        for (int tt = 0; tt < 8; ++tt) {
            int pp = seg * 8 + tt;
            int js = (pp & ~12) | ((pp & 4) << 1) | ((pp & 8) >> 1);  // swap b2,b3
            a[tt] = lds[js][dv];
        }
        uint4 st;
        st.x = (unsigned)a[0] | ((unsigned)a[1] << 16);
        st.y = (unsigned)a[2] | ((unsigned)a[3] << 16);
        st.z = (unsigned)a[4] | ((unsigned)a[5] << 16);
        st.w = (unsigned)a[6] | ((unsigned)a[7] << 16);
        *(uint4*)(vo + (size_t)dv * L_ + seg * 8) = st;
    }
}

// raw barrier: LDS-only ordering (lgkm), does NOT drain vmcnt -> the
// prefetched DMA for the next segment stays in flight across the epilogue.
#define RAWBAR() asm volatile("s_waitcnt lgkmcnt(0)\n\ts_barrier" ::: "memory")

#define LOADQ(IROW)                                                          \
{                                                                            \
    const float* qp_ = q + ((size_t)bh * L_ + (IROW)) * DK_ + hl * 8;        \
    _Pragma("unroll")                                                        \
    for (int ks = 0; ks < 8; ++ks) {                                         \
        float4 f0 = *(const float4*)(qp_ + ks * 16);                         \
        float4 f1 = *(const float4*)(qp_ + ks * 16 + 4);                     \
        union { bf16x8 v; unsigned short u[8]; } A_;                         \
        A_.u[0]=f2bf(f0.x); A_.u[1]=f2bf(f0.y); A_.u[2]=f2bf(f0.z); A_.u[3]=f2bf(f0.w); \
        A_.u[4]=f2bf(f1.x); A_.u[5]=f2bf(f1.y); A_.u[6]=f2bf(f1.z); A_.u[7]=f2bf(f1.w); \
        qf[ks] = A_.v;                                                       \
    }                                                                        \
}

#define STAGE0(OFF)                                                          \
{                                                                            \
    const char* ksrc_ = (const char*)kbp;                                    \
    const char* vsrc_ = (const char*)vtp;                                    \
    _Pragma("unroll")                                                        \
    for (int is = 0; is < 4; ++is) {                                         \
        gload_lds16(ksrc_ + koff[is], kLDSw + (OFF) + dwv[is]);              \
        gload_lds16(vsrc_ + voff[is], vLDSw + (OFF) + dwv[is]);              \
    }                                                                        \
}

#define RESETO()                                                             \
{                                                                            \
    _Pragma("unroll")                                                        \
    for (int nt = 0; nt < 4; ++nt)                                           \
        _Pragma("unroll")                                                    \
        for (int e = 0; e < 16; ++e) o[nt][e] = 0.0f;                        \
    _Pragma("unroll")                                                        \
    for (int e = 0; e < 16; ++e) o4[e] = 0.0f;                               \
}

// Shared round body: MFMA/decay/pack/PV after the wait+barrier.
#define ROUNDBODY(CUR)                                                        \
    asm volatile("s_barrier" ::: "memory");                                   \
    f32x16 s;                                                                 \
    _Pragma("unroll")                                                         \
    for (int e = 0; e < 16; ++e) s[e] = 0.0f;                                 \
    __builtin_amdgcn_s_setprio(1);                                            \
    _Pragma("unroll")                                                         \
    for (int ks = 0; ks < 8; ++ks)                                            \
        s = __builtin_amdgcn_mfma_f32_32x32x16_bf16(                          \
                *(const bf16x8*)(ka[ks] + (CUR)), qf[ks], s, 0, 0, 0);        \
    __builtin_amdgcn_s_setprio(0);                                            \
    float ab = arow;                                                          \
    arow *= gm64i;                                                            \
    float val[16];                                                            \
    if (jt == itile) {                                                        \
        _Pragma("unroll")                                                     \
        for (int r = 0; r < 16; ++r) {                                        \
            float vv = s[r] * ab;                                             \
            val[r] = ((mbits >> r) & 1) ? vv : 0.0f;                          \
        }                                                                     \
    } else {                                                                  \
        _Pragma("unroll")                                                     \
        for (int r = 0; r < 16; ++r) val[r] = s[r] * ab;                      \
    }                                                                         \
    union { bf16x8 v; __bf16 e[8]; } P0, P1;                                  \
    _Pragma("unroll")                                                         \
    for (int e = 0; e < 8; ++e) { P0.e[e] = (__bf16)val[e];                   \
                                  P1.e[e] = (__bf16)val[8 + e]; }             \
    __builtin_amdgcn_s_setprio(1);                                            \
    _Pragma("unroll")                                                         \
    for (int nt = 0; nt < 4; ++nt) {                                          \
        o[nt] = __builtin_amdgcn_mfma_f32_32x32x16_bf16(                      \
                    P0.v, *(const bf16x8*)(va0[nt] + (CUR)), o[nt], 0, 0, 0); \
        o[nt] = __builtin_amdgcn_mfma_f32_32x32x16_bf16(                      \
                    P1.v, *(const bf16x8*)(va1[nt] + (CUR)), o[nt], 0, 0, 0); \
    }                                                                         \
    o4 = __builtin_amdgcn_mfma_f32_32x32x16_bf16(P0.v, onesv, o4, 0, 0, 0);   \
    o4 = __builtin_amdgcn_mfma_f32_32x32x16_bf16(P1.v, onesv, o4, 0, 0, 0);   \
    __builtin_amdgcn_s_setprio(0);                                            \
    asm volatile("s_barrier" ::: "memory");

// Segment-B round: stage jt+1 while jt<itile, else final vmcnt(0) drain.
#define ROUND(CUR, NXT)                                                       \
{                                                                             \
    if (jt < itile) {                                                         \
        const char* ksrc = (const char*)(kbp + (size_t)(jt + 1) * KVBLK * DK_);\
        const char* vsrc = (const char*)(vtp + (jt + 1) * KVBLK);             \
        _Pragma("unroll")                                                     \
        for (int is = 0; is < 4; ++is) {                                      \
            gload_lds16(ksrc + koff[is], kLDSw + (NXT) + dwv[is]);            \
            gload_lds16(vsrc + voff[is], vLDSw + (NXT) + dwv[is]);            \
        }                                                                     \
        asm volatile("s_waitcnt vmcnt(8)" ::: "memory");                      \
    } else {                                                                  \
        asm volatile("s_waitcnt vmcnt(0)" ::: "memory");                      \
    }                                                                         \
    ROUNDBODY(CUR)                                                            \
}

// Segment-A round: CONTINUOUS staging -- the tile after A's diagonal is
// seg-B tile 0 (jn_ wraps to 0), so every A-round stages and waits the
// counted vmcnt(8); no mid-kernel vmcnt(0) drain. Buffer ledger identical
// to the standard protocol (NXT last read in round jt-1, guarded by its
// trailing barrier).
#define ROUNDA(CUR, NXT)                                                      \
{                                                                             \
    int jn_ = jt + 1; if (jn_ > itile) jn_ = 0;                               \
    const char* ksrc = (const char*)(kbp + (size_t)jn_ * KVBLK * DK_);        \
    const char* vsrc = (const char*)(vtp + jn_ * KVBLK);                      \
    _Pragma("unroll")                                                         \
    for (int is = 0; is < 4; ++is) {                                          \
        gload_lds16(ksrc + koff[is], kLDSw + (NXT) + dwv[is]);                \
        gload_lds16(vsrc + voff[is], vLDSw + (NXT) + dwv[is]);                \
    }                                                                         \
    asm volatile("s_waitcnt vmcnt(8)" ::: "memory");                          \
    ROUNDBODY(CUR)                                                            \
}

// Epilogue: cross-kh reduce via LDS exchange at byte offset EXOFF (the
// buffer half NOT holding the prefetched next-segment tile), then
// normalize + RMSNorm + store. rh0 in kbuf+EXOFF, rh1 in vbuf+EXOFF.
#define EPILOGUE(IBASE, EXOFF)                                                \
{                                                                             \
    RAWBAR();                                                                 \
    float* eb = (float*)((rh ? vLDSw : kLDSw) + (EXOFF));                     \
    if (kh == 1) {                                                            \
        _Pragma("unroll")                                                     \
        for (int nt = 0; nt < 4; ++nt)                                        \
            _Pragma("unroll")                                                 \
            for (int qq = 0; qq < 4; ++qq) {                                  \
                float4 vv = { o[nt][4*qq+0], o[nt][4*qq+1],                   \
                              o[nt][4*qq+2], o[nt][4*qq+3] };                 \
                *(float4*)(eb + (nt * 4 + qq) * 256 + lane * 4) = vv;         \
            }                                                                 \
        if (lane == 0) {                                                      \
            _Pragma("unroll")                                                 \
            for (int r = 0; r < 16; ++r) rsx[rh * 16 + r] = o4[r];            \
        }                                                                     \
    }                                                                         \
    RAWBAR();                                                                 \
    if (kh == 0) {                                                            \
        _Pragma("unroll")                                                     \
        for (int nt = 0; nt < 4; ++nt)                                        \
            _Pragma("unroll")                                                 \
            for (int qq = 0; qq < 4; ++qq) {                                  \
                float4 pv = *(const float4*)(eb + (nt * 4 + qq) * 256 + lane * 4); \
                o[nt][4*qq+0] += pv.x; o[nt][4*qq+1] += pv.y;                 \
                o[nt][4*qq+2] += pv.z; o[nt][4*qq+3] += pv.w;                 \
            }                                                                 \
        _Pragma("unroll")                                                     \
        for (int r = 0; r < 16; ++r) {                                        \
            float rtot = o4[r] + rsx[rh * 16 + r];                            \
            float dn = 1.0f / fmaxf(1.0f, fabsf(rtot));                       \
            float ov[4]; float ss = 0.0f;                                     \
            _Pragma("unroll")                                                 \
            for (int nt = 0; nt < 4; ++nt) { ov[nt] = o[nt][r] * dn; ss += ov[nt]*ov[nt]; } \
            ss += __shfl_xor(ss, 1);  ss += __shfl_xor(ss, 2);                \
            ss += __shfl_xor(ss, 4);  ss += __shfl_xor(ss, 8);                \
            ss += __shfl_xor(ss, 16);                                         \
            float sc = rsqrtf(ss * (1.0f / 128.0f) + 1e-6f);                  \
            int isrc = (r & 3) + 8 * (r >> 2) + 4 * hl;                       \
            int i_abs = (IBASE) + isrc;                                       \
            if (i_abs != 0) {               /* row 0 handled in prep (fp32) */\
                float* op = out + (((size_t)b * L_ + i_abs) * H_ + h) * DV_ + il; \
                _Pragma("unroll")                                             \
                for (int nt = 0; nt < 4; ++nt) op[nt * 32] = ov[nt] * sc;     \
            }                                                                 \
        }                                                                     \
    }                                                                         \
    RAWBAR();   /* exchange reads done before this memory is restaged */      \
}

// ---- main kernel: r10 geometry -- 4 waves (rh,kh), QBLK=64, KVBLK=64,
// K/V dbuf, balanced q-tile pairs {sp,31-sp}, grid 512 = 2/CU, 2 waves/
// SIMD, r14 VALU diet, r18 boundary overlap. NEW: continuous cross-
// segment staging (A's diagonal round stages seg-B tile 0, vmcnt(8)
// everywhere in segment A -- no mid-kernel vmcnt(0) drain).
__launch_bounds__(256, 2)
__global__ void retention_kernel(const float* __restrict__ q,
                                 const unsigned short* __restrict__ kb,
                                 const unsigned short* __restrict__ vt_,
                                 float* __restrict__ out) {
    __shared__ __align__(16) unsigned short kbuf[2][64 * 128];   // 32 KB
    __shared__ __align__(16) unsigned short vbuf[2][128 * 64];   // 32 KB
    __shared__ float rsx[32];

    // bh->XCD-pinned remap (xcd = bid%8): 4 bh per XCD -> ~4MB K+V ~= L2
    int bid = blockIdx.x;            // 0..511
    int x   = bid & 7;               // XCD id
    int t_  = bid >> 3;              // 0..63
    int hi  = t_ >> 4;               // 0..3
    int sp  = t_ & 15;               // 0..15: q-tile pair (sp, 31-sp)
    int bh = hi * 8 + x;
    int b = bh >> 4, h = bh & 15;

    int tid = threadIdx.x;
    int lane = tid & 63;
    int w = tid >> 6;                   // 0..3
    int rh = w >> 1;                    // q-row half
    int kh = w & 1;                     // kv half
    int il = lane & 31;
    int hl = lane >> 5;

    const unsigned short* kbp = kb  + (size_t)bh * L_ * DK_;
    const unsigned short* vtp = vt_ + (size_t)bh * DV_ * L_;

    // hoisted per-lane stage offsets (loop-invariant)
    int dwv[4], koff[4], voff[4];
    #pragma unroll
    for (int is = 0; is < 4; ++is) {
        int dw = is * 4096 + w * 1024;
        int d  = dw + lane * 16;
        dwv[is]  = dw;
        koff[is] = KSWZ(d);
        int sv   = VSWZ(d);
        voff[is] = (sv >> 7) * (L_ * 2) + (sv & 127);
    }
    char* kLDSw = (char*)&kbuf[0][0];
    char* vLDSw = (char*)&vbuf[0][0];

    float ex = exp2f((float)(-5 - h));
    float log2g = log1pf(-ex) * 1.44269504088896f;
    float gm64i = exp2f(log2g * (-64.0f));

    // diag mask (segment-invariant): keep iff j_local <= i_local
    int icmp = rh * 32 + il - kh * 32;
    unsigned mbits = 0;
    #pragma unroll
    for (int r = 0; r < 16; ++r)
        if (((r & 3) + 8 * (r >> 2) + 4 * hl) <= icmp) mbits |= 1u << r;

    int rswz = (il & 7) << 4;           // read-side XOR (rows == il mod 8)
    int hl16 = hl * 16;

    // hoisted LDS read addresses (buffer picked via +0/+16384 literal)
    const char* ka[8];
    #pragma unroll
    for (int ks = 0; ks < 8; ++ks)
        ka[ks] = (const char*)&kbuf[0][0] + (kh * 32 + il) * 256
                 + ((ks * 32 + hl16) ^ rswz);
    const char* va0[4];
    const char* va1[4];
    #pragma unroll
    for (int nt = 0; nt < 4; ++nt) {
        va0[nt] = (const char*)&vbuf[0][0] + (nt * 32 + il) * 128
                  + ((kh * 64 + hl16) ^ rswz);
        va1[nt] = (const char*)&vbuf[0][0] + (nt * 32 + il) * 128
                  + ((kh * 64 + 32 + hl16) ^ rswz);
    }

    union { bf16x8 v; __bf16 e[8]; } ones_;
    #pragma unroll
    for (int e = 0; e < 8; ++e) ones_.e[e] = (__bf16)1.0f;
    bf16x8 onesv = ones_.v;

    int itileA = sp;                 // 0..15
    int itileB = 31 - sp;            // 16..31
    int i0A = itileA * QBLK + rh * 32;
    int i0B = itileB * QBLK + rh * 32;

    bf16x8 qf[8];
    f32x16 o[4], o4;
    float arow;

    // ================= segment A =================
    LOADQ(i0A + il);                 // Q first: its waits drain nothing of ours
    STAGE0(0);
    arow = exp2f(log2g * (float)(i0A + il));
    RESETO();
    {
        int itile = itileA;
        int jt = 0;
        while (true) {               // continuous staging: wraps to B tile 0
            ROUNDA(0, 16384);
            if (++jt > itile) break;
            ROUNDA(16384, 0);
            if (++jt > itile) break;
        }
    }

    // ---- boundary: seg-B tile 0 already in flight (staged by A's diagonal
    // round). Q-load B here; its implicit waits find the DMA ~1 round old.
    LOADQ(i0B + il);
    int startB = ((itileA + 1) & 1) * 16384;   // where A's last round staged
    int exA    = (itileA & 1) * 16384;         // last-read half -> exchange

    EPILOGUE(i0A, exA);

    // ================= segment B =================
    arow = exp2f(log2g * (float)(i0B + il));
    RESETO();
    {
        int itile = itileB;
        int jt = 0;
        if (startB == 0) {
            while (true) {
                ROUND(0, 16384);
                if (++jt > itile) break;
                ROUND(16384, 0);
                if (++jt > itile) break;
            }
        } else {
            while (true) {
                ROUND(16384, 0);
                if (++jt > itile) break;
                ROUND(0, 16384);
                if (++jt > itile) break;
            }
        }
    }
    EPILOGUE(i0B, 0);
}

extern "C" void kernel_launch(void* const* d_in, const int* in_sizes, int n_in,
                              void* d_out, int out_size, void* d_ws, size_t ws_size,
                              hipStream_t stream) {
    const float* q = (const float*)d_in[0];
    const float* k = (const float*)d_in[1];
    const float* v = (const float*)d_in[2];
    // d_in[3] decay_mask (256MB) and d_in[4] intra_decay are recomputed on the fly
    float* out = (float*)d_out;

    unsigned short* kb = (unsigned short*)d_ws;                 // 16 MB
    unsigned short* vt = kb + (size_t)B_ * H_ * L_ * DK_;       // 16 MB

    prep_kernel<<<2080, 256, 0, stream>>>(k, kb, v, vt, q, out);
    retention_kernel<<<512, 256, 0, stream>>>(q, kb, vt, out);
}

// Round 20
// 79.250 us; speedup vs baseline: 1.0245x; 1.0245x over previous
//
#include <hip/hip_runtime.h>
#include <hip/hip_bf16.h>
#include <math.h>

// SelfRetentionV1: B=2,H=16,L=2048,DK=128,DV=128
// out[b,l,h,d] = RMSNorm_d( (QK^T * gamma^(i-j) / max(1,|rowsum|)) @ V )
#define B_ 2
#define H_ 16
#define L_ 2048
#define DK_ 128
#define DV_ 128
#define QBLK 64
#define KVBLK 64

typedef __bf16 bf16x8 __attribute__((ext_vector_type(8)));
typedef float  f32x16 __attribute__((ext_vector_type(16)));

static __device__ __forceinline__ unsigned short f2bf(float f) {
    union { float f; unsigned int u; } x; x.f = f;
    unsigned int r = x.u + 0x7fffu + ((x.u >> 16) & 1u);  // RNE
    return (unsigned short)(r >> 16);
}

// async global->LDS, 16B per lane; LDS dest = wave-uniform base + lane*16
static __device__ __forceinline__ void gload_lds16(const void* g, void* l) {
    __builtin_amdgcn_global_load_lds(
        (const __attribute__((address_space(1))) unsigned int*)g,
        (__attribute__((address_space(3))) unsigned int*)l,
        16, 0, 0);
}

// K tile rows are 256B: swizzle bits 4-6 by row&7 (involution, row bits >=8)
#define KSWZ(d) ((d) ^ ((((d) >> 8) & 7) << 4))
// V tile rows are 128B: row bits >=7
#define VSWZ(d) ((d) ^ ((((d) >> 7) & 7) << 4))

// ---- fused pre-pass: blocks 0..1023 convert K fp32->bf16 SCALED BY
// gamma_h^-(j&63); 1024..2047 transpose V -> VT[bh][dv][perm(l)]
// (bit2<->3 perm); 2048..2079 fp32 row-0 fixup ----
__global__ void prep_kernel(const float* __restrict__ kin,
                            unsigned short* __restrict__ kb,
                            const float* __restrict__ v,
                            unsigned short* __restrict__ vt,
                            const float* __restrict__ q,
                            float* __restrict__ out) {
    __shared__ unsigned short lds[64][130];   // +2 pad (transpose half only)
    int bid = blockIdx.x;
    if (bid >= 2048) {                 // row-0 fixup, 32 blocks, wave 0 only
        if (threadIdx.x < 64) {
            int bh = bid - 2048;
            int lane = threadIdx.x;
            const float* qp = q   + (size_t)bh * L_ * DK_;
            const float* kp = kin + (size_t)bh * L_ * DK_;
            const float* vp = v   + (size_t)bh * L_ * DV_;
            float part = qp[lane] * kp[lane] + qp[lane + 64] * kp[lane + 64];
            #pragma unroll
            for (int mm = 1; mm < 64; mm <<= 1) part += __shfl_xor(part, mm);
            float cf = part / fmaxf(1.0f, fabsf(part));
            float o0 = cf * vp[lane], o1 = cf * vp[lane + 64];
            float ss = o0 * o0 + o1 * o1;
            #pragma unroll
            for (int mm = 1; mm < 64; mm <<= 1) ss += __shfl_xor(ss, mm);
            float sc = rsqrtf(ss * (1.0f / 128.0f) + 1e-6f);
            int b = bh >> 4, h = bh & 15;
            float* op = out + ((size_t)b * L_ * H_ + h) * DV_;   // i = 0
            op[lane] = o0 * sc;
            op[lane + 64] = o1 * sc;
        }
        return;
    }
    if (bid < 1024) {
        // element layout [b][h][l][dk]: j = (i>>5)&2047, h = (i>>16)&15
        int n4 = B_ * H_ * L_ * DK_ / 4;
        int i = bid * 256 + threadIdx.x;
        int stride = 1024 * 256;
        for (; i < n4; i += stride) {
            int j = (i >> 5) & (L_ - 1);
            int h = (i >> 16) & (H_ - 1);
            float l2g = log1pf(-exp2f((float)(-5 - h))) * 1.44269504088896f;
            float s = exp2f(l2g * -(float)(j & 63));   // gamma^-(j mod 64)
            float4 f = ((const float4*)kin)[i];
            uint2 o;
            o.x = (unsigned)f2bf(f.x * s) | ((unsigned)f2bf(f.y * s) << 16);
            o.y = (unsigned)f2bf(f.z * s) | ((unsigned)f2bf(f.w * s) << 16);
            ((uint2*)kb)[i] = o;
        }
        return;
    }
    int blk = bid - 1024;
    int ltile = blk & (L_/64 - 1);
    int bh = blk / (L_/64);
    const float* vp = v + ((size_t)bh * L_ + (size_t)ltile * 64) * DV_;
    unsigned short* vo = vt + (size_t)bh * DV_ * L_ + ltile * 64;
    int t = threadIdx.x;
    int r0 = t >> 5, c0 = (t & 31) * 4;
    #pragma unroll
    for (int it = 0; it < 8; ++it) {
        int row = r0 + 8 * it;
        float4 f = *(const float4*)(vp + row * DV_ + c0);
        lds[row][c0 + 0] = f2bf(f.x);
        lds[row][c0 + 1] = f2bf(f.y);
        lds[row][c0 + 2] = f2bf(f.z);
        lds[row][c0 + 3] = f2bf(f.w);
    }
    __syncthreads();
    int dvb = t >> 3, seg = t & 7;
    #pragma unroll
    for (int ot = 0; ot < 4; ++ot) {
        int dv = dvb + 32 * ot;
        unsigned short a[8];
        #pragma unroll
        for (int tt = 0; tt < 8; ++tt) {
            int pp = seg * 8 + tt;
            int js = (pp & ~12) | ((pp & 4) << 1) | ((pp & 8) >> 1);  // swap b2,b3
            a[tt] = lds[js][dv];
        }
        uint4 st;
        st.x = (unsigned)a[0] | ((unsigned)a[1] << 16);
        st.y = (unsigned)a[2] | ((unsigned)a[3] << 16);
        st.z = (unsigned)a[4] | ((unsigned)a[5] << 16);
        st.w = (unsigned)a[6] | ((unsigned)a[7] << 16);
        *(uint4*)(vo + (size_t)dv * L_ + seg * 8) = st;
    }
}

// raw barrier: LDS-only ordering (lgkm), does NOT drain vmcnt -> the
// prefetched DMA for the next segment stays in flight across the epilogue.
// Safe for the exchange: every tile ds_read is consumed by an MFMA whose
// compiler-inserted lgkm wait retires it before that wave's final s_barrier.
#define RAWBAR() asm volatile("s_waitcnt lgkmcnt(0)\n\ts_barrier" ::: "memory")

#define LOADQ(IROW)                                                          \
{                                                                            \
    const float* qp_ = q + ((size_t)bh * L_ + (IROW)) * DK_ + hl * 8;        \
    _Pragma("unroll")                                                        \
    for (int ks = 0; ks < 8; ++ks) {                                         \
        float4 f0 = *(const float4*)(qp_ + ks * 16);                         \
        float4 f1 = *(const float4*)(qp_ + ks * 16 + 4);                     \
        union { bf16x8 v; unsigned short u[8]; } A_;                         \
        A_.u[0]=f2bf(f0.x); A_.u[1]=f2bf(f0.y); A_.u[2]=f2bf(f0.z); A_.u[3]=f2bf(f0.w); \
        A_.u[4]=f2bf(f1.x); A_.u[5]=f2bf(f1.y); A_.u[6]=f2bf(f1.z); A_.u[7]=f2bf(f1.w); \
        qf[ks] = A_.v;                                                       \
    }                                                                        \
}

#define STAGE0(OFF)                                                          \
{                                                                            \
    const char* ksrc_ = (const char*)kbp;                                    \
    const char* vsrc_ = (const char*)vtp;                                    \
    _Pragma("unroll")                                                        \
    for (int is = 0; is < 4; ++is) {                                         \
        gload_lds16(ksrc_ + koff[is], kLDSw + (OFF) + dwv[is]);              \
        gload_lds16(vsrc_ + voff[is], vLDSw + (OFF) + dwv[is]);              \
    }                                                                        \
}

#define RESETO()                                                             \
{                                                                            \
    _Pragma("unroll")                                                        \
    for (int nt = 0; nt < 4; ++nt)                                           \
        _Pragma("unroll")                                                    \
        for (int e = 0; e < 16; ++e) o[nt][e] = 0.0f;                        \
    _Pragma("unroll")                                                        \
    for (int e = 0; e < 16; ++e) o4[e] = 0.0f;                               \
}

// One pipeline round at static buffer offset CUR (0 / 16384), staging the
// next tile into NXT. Protocol = proven r10/r14: vmcnt(8) counted wait
// (never drains the fresh stage), 2 s_barrier. Decay is ONE mul (colfac
// folded into kb by prep); rowsum rides the matrix pipe via mfma(P, ones).
#define ROUND(CUR, NXT)                                                       \
{                                                                             \
    if (jt < itile) {                                                         \
        const char* ksrc = (const char*)(kbp + (size_t)(jt + 1) * KVBLK * DK_);\
        const char* vsrc = (const char*)(vtp + (jt + 1) * KVBLK);             \
        _Pragma("unroll")                                                     \
        for (int is = 0; is < 4; ++is) {                                      \
            gload_lds16(ksrc + koff[is], kLDSw + (NXT) + dwv[is]);            \
            gload_lds16(vsrc + voff[is], vLDSw + (NXT) + dwv[is]);            \
        }                                                                     \
        asm volatile("s_waitcnt vmcnt(8)" ::: "memory");                      \
    } else {                                                                  \
        asm volatile("s_waitcnt vmcnt(0)" ::: "memory");                      \
    }                                                                         \
    asm volatile("s_barrier" ::: "memory");                                   \
    f32x16 s;                                                                 \
    _Pragma("unroll")                                                         \
    for (int e = 0; e < 16; ++e) s[e] = 0.0f;                                 \
    __builtin_amdgcn_s_setprio(1);                                            \
    _Pragma("unroll")                                                         \
    for (int ks = 0; ks < 8; ++ks)                                            \
        s = __builtin_amdgcn_mfma_f32_32x32x16_bf16(                          \
                *(const bf16x8*)(ka[ks] + (CUR)), qf[ks], s, 0, 0, 0);        \
    __builtin_amdgcn_s_setprio(0);                                            \
    float ab = arow;                                                          \
    arow *= gm64i;                                                            \
    float val[16];                                                            \
    if (jt == itile) {                                                        \
        _Pragma("unroll")                                                     \
        for (int r = 0; r < 16; ++r) {                                        \
            float vv = s[r] * ab;                                             \
            val[r] = ((mbits >> r) & 1) ? vv : 0.0f;                          \
        }                                                                     \
    } else {                                                                  \
        _Pragma("unroll")                                                     \
        for (int r = 0; r < 16; ++r) val[r] = s[r] * ab;                      \
    }                                                                         \
    union { bf16x8 v; __bf16 e[8]; } P0, P1;                                  \
    _Pragma("unroll")                                                         \
    for (int e = 0; e < 8; ++e) { P0.e[e] = (__bf16)val[e];                   \
                                  P1.e[e] = (__bf16)val[8 + e]; }             \
    __builtin_amdgcn_s_setprio(1);                                            \
    _Pragma("unroll")                                                         \
    for (int nt = 0; nt < 4; ++nt) {                                          \
        o[nt] = __builtin_amdgcn_mfma_f32_32x32x16_bf16(                      \
                    P0.v, *(const bf16x8*)(va0[nt] + (CUR)), o[nt], 0, 0, 0); \
        o[nt] = __builtin_amdgcn_mfma_f32_32x32x16_bf16(                      \
                    P1.v, *(const bf16x8*)(va1[nt] + (CUR)), o[nt], 0, 0, 0); \
    }                                                                         \
    o4 = __builtin_amdgcn_mfma_f32_32x32x16_bf16(P0.v, onesv, o4, 0, 0, 0);   \
    o4 = __builtin_amdgcn_mfma_f32_32x32x16_bf16(P1.v, onesv, o4, 0, 0, 0);   \
    __builtin_amdgcn_s_setprio(0);                                            \
    asm volatile("s_barrier" ::: "memory");                                   \
}

// Epilogue: cross-kh reduce via LDS exchange at byte offset EXOFF (the
// buffer half NOT being prefetched into), then normalize + RMSNorm + store.
// rh0 exchanges in kbuf+EXOFF, rh1 in vbuf+EXOFF (16KB each).
#define EPILOGUE(IBASE, EXOFF)                                                \
{                                                                             \
    RAWBAR();                                                                 \
    float* eb = (float*)((rh ? vLDSw : kLDSw) + (EXOFF));                     \
    if (kh == 1) {                                                            \
        _Pragma("unroll")                                                     \
        for (int nt = 0; nt < 4; ++nt)                                        \
            _Pragma("unroll")                                                 \
            for (int qq = 0; qq < 4; ++qq) {                                  \
                float4 vv = { o[nt][4*qq+0], o[nt][4*qq+1],                   \
                              o[nt][4*qq+2], o[nt][4*qq+3] };                 \
                *(float4*)(eb + (nt * 4 + qq) * 256 + lane * 4) = vv;         \
            }                                                                 \
        if (lane == 0) {                                                      \
            _Pragma("unroll")                                                 \
            for (int r = 0; r < 16; ++r) rsx[rh * 16 + r] = o4[r];            \
        }                                                                     \
    }                                                                         \
    RAWBAR();                                                                 \
    if (kh == 0) {                                                            \
        _Pragma("unroll")                                                     \
        for (int nt = 0; nt < 4; ++nt)                                        \
            _Pragma("unroll")                                                 \
            for (int qq = 0; qq < 4; ++qq) {                                  \
                float4 pv = *(const float4*)(eb + (nt * 4 + qq) * 256 + lane * 4); \
                o[nt][4*qq+0] += pv.x; o[nt][4*qq+1] += pv.y;                 \
                o[nt][4*qq+2] += pv.z; o[nt][4*qq+3] += pv.w;                 \
            }                                                                 \
        _Pragma("unroll")                                                     \
        for (int r = 0; r < 16; ++r) {                                        \
            float rtot = o4[r] + rsx[rh * 16 + r];                            \
            float dn = 1.0f / fmaxf(1.0f, fabsf(rtot));                       \
            float ov[4]; float ss = 0.0f;                                     \
            _Pragma("unroll")                                                 \
            for (int nt = 0; nt < 4; ++nt) { ov[nt] = o[nt][r] * dn; ss += ov[nt]*ov[nt]; } \
            ss += __shfl_xor(ss, 1);  ss += __shfl_xor(ss, 2);                \
            ss += __shfl_xor(ss, 4);  ss += __shfl_xor(ss, 8);                \
            ss += __shfl_xor(ss, 16);                                         \
            float sc = rsqrtf(ss * (1.0f / 128.0f) + 1e-6f);                  \
            int isrc = (r & 3) + 8 * (r >> 2) + 4 * hl;                       \
            int i_abs = (IBASE) + isrc;                                       \
            if (i_abs != 0) {               /* row 0 handled in prep (fp32) */\
                float* op = out + (((size_t)b * L_ + i_abs) * H_ + h) * DV_ + il; \
                _Pragma("unroll")                                             \
                for (int nt = 0; nt < 4; ++nt) op[nt * 32] = ov[nt] * sc;     \
            }                                                                 \
        }                                                                     \
    }                                                                         \
    RAWBAR();   /* exchange reads done before this memory is restaged */      \
}

// ---- main kernel: r18 exact (best measured: 79.18us) -- 4 waves (rh,kh),
// QBLK=64, KVBLK=64, K/V dbuf, balanced q-tile pairs {sp,31-sp}, grid 512
// = 2/CU, 2 waves/SIMD, r14 VALU diet, r18 boundary overlap (seg-B Q load
// + tile-0 DMA issued before epilogue A; raw lgkm-only epilogue barriers).
// r19's continuous cross-segment staging REVERTED: it moved the vmcnt
// drain earlier (before the diagonal's MFMAs) and regressed 2us.
__launch_bounds__(256, 2)
__global__ void retention_kernel(const float* __restrict__ q,
                                 const unsigned short* __restrict__ kb,
                                 const unsigned short* __restrict__ vt_,
                                 float* __restrict__ out) {
    __shared__ __align__(16) unsigned short kbuf[2][64 * 128];   // 32 KB
    __shared__ __align__(16) unsigned short vbuf[2][128 * 64];   // 32 KB
    __shared__ float rsx[32];

    // bh->XCD-pinned remap (xcd = bid%8): 4 bh per XCD -> ~4MB K+V ~= L2
    int bid = blockIdx.x;            // 0..511
    int x   = bid & 7;               // XCD id
    int t_  = bid >> 3;              // 0..63
    int hi  = t_ >> 4;               // 0..3
    int sp  = t_ & 15;               // 0..15: q-tile pair (sp, 31-sp)
    int bh = hi * 8 + x;
    int b = bh >> 4, h = bh & 15;

    int tid = threadIdx.x;
    int lane = tid & 63;
    int w = tid >> 6;                   // 0..3
    int rh = w >> 1;                    // q-row half
    int kh = w & 1;                     // kv half
    int il = lane & 31;
    int hl = lane >> 5;

    const unsigned short* kbp = kb  + (size_t)bh * L_ * DK_;
    const unsigned short* vtp = vt_ + (size_t)bh * DV_ * L_;

    // hoisted per-lane stage offsets (loop-invariant)
    int dwv[4], koff[4], voff[4];
    #pragma unroll
    for (int is = 0; is < 4; ++is) {
        int dw = is * 4096 + w * 1024;
        int d  = dw + lane * 16;
        dwv[is]  = dw;
        koff[is] = KSWZ(d);
        int sv   = VSWZ(d);
        voff[is] = (sv >> 7) * (L_ * 2) + (sv & 127);
    }
    char* kLDSw = (char*)&kbuf[0][0];
    char* vLDSw = (char*)&vbuf[0][0];

    float ex = exp2f((float)(-5 - h));
    float log2g = log1pf(-ex) * 1.44269504088896f;
    float gm64i = exp2f(log2g * (-64.0f));

    // diag mask (segment-invariant): keep iff j_local <= i_local
    int icmp = rh * 32 + il - kh * 32;
    unsigned mbits = 0;
    #pragma unroll
    for (int r = 0; r < 16; ++r)
        if (((r & 3) + 8 * (r >> 2) + 4 * hl) <= icmp) mbits |= 1u << r;

    int rswz = (il & 7) << 4;           // read-side XOR (rows == il mod 8)
    int hl16 = hl * 16;

    // hoisted LDS read addresses (buffer picked via +0/+16384 literal)
    const char* ka[8];
    #pragma unroll
    for (int ks = 0; ks < 8; ++ks)
        ka[ks] = (const char*)&kbuf[0][0] + (kh * 32 + il) * 256
                 + ((ks * 32 + hl16) ^ rswz);
    const char* va0[4];
    const char* va1[4];
    #pragma unroll
    for (int nt = 0; nt < 4; ++nt) {
        va0[nt] = (const char*)&vbuf[0][0] + (nt * 32 + il) * 128
                  + ((kh * 64 + hl16) ^ rswz);
        va1[nt] = (const char*)&vbuf[0][0] + (nt * 32 + il) * 128
                  + ((kh * 64 + 32 + hl16) ^ rswz);
    }

    union { bf16x8 v; __bf16 e[8]; } ones_;
    #pragma unroll
    for (int e = 0; e < 8; ++e) ones_.e[e] = (__bf16)1.0f;
    bf16x8 onesv = ones_.v;

    int itileA = sp;                 // 0..15
    int itileB = 31 - sp;            // 16..31
    int i0A = itileA * QBLK + rh * 32;
    int i0B = itileB * QBLK + rh * 32;

    bf16x8 qf[8];
    f32x16 o[4], o4;
    float arow;

    // ================= segment A =================
    LOADQ(i0A + il);                 // Q first: its waits drain nothing of ours
    STAGE0(0);
    arow = exp2f(log2g * (float)(i0A + il));
    RESETO();
    {
        int itile = itileA;
        int jt = 0;
        while (true) {
            ROUND(0, 16384);
            if (++jt > itile) break;
            ROUND(16384, 0);
            if (++jt > itile) break;
        }
    }

    // ---- boundary: prefetch seg B under epilogue A ----
    // last round drained vmcnt(0): zero outstanding -> LOADQ's implicit
    // waits are free; then tile-0-B DMA targets the free buffer half.
    LOADQ(i0B + il);
    int startB = ((itileA + 1) & 1) * 16384;   // free buffer half
    int exA    = (itileA & 1) * 16384;         // last-read half -> exchange
    STAGE0(startB);

    EPILOGUE(i0A, exA);

    // ================= segment B =================
    arow = exp2f(log2g * (float)(i0B + il));
    RESETO();
    {
        int itile = itileB;
        int jt = 0;
        if (startB == 0) {
            while (true) {
                ROUND(0, 16384);
                if (++jt > itile) break;
                ROUND(16384, 0);
                if (++jt > itile) break;
            }
        } else {
            while (true) {
                ROUND(16384, 0);
                if (++jt > itile) break;
                ROUND(0, 16384);
                if (++jt > itile) break;
            }
        }
    }
    EPILOGUE(i0B, 0);
}

extern "C" void kernel_launch(void* const* d_in, const int* in_sizes, int n_in,
                              void* d_out, int out_size, void* d_ws, size_t ws_size,
                              hipStream_t stream) {
    const float* q = (const float*)d_in[0];
    const float* k = (const float*)d_in[1];
    const float* v = (const float*)d_in[2];
    // d_in[3] decay_mask (256MB) and d_in[4] intra_decay are recomputed on the fly
    float* out = (float*)d_out;

    unsigned short* kb = (unsigned short*)d_ws;                 // 16 MB
    unsigned short* vt = kb + (size_t)B_ * H_ * L_ * DK_;       // 16 MB

    prep_kernel<<<2080, 256, 0, stream>>>(k, kb, v, vt, q, out);
    retention_kernel<<<512, 256, 0, stream>>>(q, kb, vt, out);
}